// Round 1
// baseline (475.985 us; speedup 1.0000x reference)
//
#include <hip/hip_runtime.h>

// Problem constants (from reference)
#define EPSF 1e-20f
constexpr int V = 96, K = 20, D = 1024, B = 256;
constexpr int E_DIM = 4, N_DIM = 2, C_DIM = 2;
constexpr int VK = V * K;                 // 1920 floats per (i,j,e,n,c,b) slab
constexpr int ENC = E_DIM * N_DIM * C_DIM; // 16
constexpr int NBLK_MAIN = 9 * ENC * B;    // 36864
constexpr int NSLOTS = 256;               // fp64 accumulator slots

// ---------------------------------------------------------------------------
// 0) zero the fp64 accumulator slots (ws is re-poisoned 0xAA before each call)
__global__ void zero_acc_kernel(double* __restrict__ acc) {
    acc[threadIdx.x] = 0.0;
}

// ---------------------------------------------------------------------------
// 1) y_tr[ij][d] = sum over (e,n,c,v) of Y[i,j,e,n,c,d,v]
//    One 64-thread block per (ij,d); 16 rows of 96 floats = 384 float4 loads.
__global__ __launch_bounds__(64) void ytr_kernel(const float* __restrict__ Y,
                                                 float* __restrict__ y_tr) {
    const int blk = blockIdx.x;        // ij*D + d
    const int d = blk % D;
    const int ij = blk / D;
    const int tid = threadIdx.x;
    const float4* __restrict__ base = (const float4*)Y;
    float s = 0.f;
#pragma unroll
    for (int it = 0; it < 6; ++it) {
        int idx4 = tid + it * 64;          // [0, 384)
        int enc = idx4 / 24;               // 24 float4 per 96-float row
        int v4 = idx4 % 24;
        size_t off4 = (((size_t)(ij * ENC + enc) * D + d) * V) / 4 + v4;
        float4 y = base[off4];
        s += y.x + y.y + y.z + y.w;
    }
#pragma unroll
    for (int off = 32; off; off >>= 1) s += __shfl_down(s, off, 64);
    if (tid == 0) y_tr[blk] = s;
}

// ---------------------------------------------------------------------------
// 2) mr[2][2][D] from y_tr
__global__ void mr_kernel(const float* __restrict__ y_tr, float* __restrict__ mr) {
    int d = blockIdx.x * blockDim.x + threadIdx.x;
    if (d >= D) return;
    float y[9];
    float tot = 0.f;
#pragma unroll
    for (int ij = 0; ij < 9; ++ij) { y[ij] = y_tr[ij * D + d]; tot += y[ij]; }
    mr[0 * D + d] = (y[0] + y[1] + y[3] + y[4]) / tot;  // m00: (0,0)(0,1)(1,0)(1,1)
    mr[1 * D + d] = (y[2] + y[5]) / tot;                // m01: (0,2)(1,2)
    mr[2 * D + d] = (y[6] + y[7]) / tot;                // m10: (2,0)(2,1)
    mr[3 * D + d] = y[8] / tot;                         // m11: (2,2)
}

// ---------------------------------------------------------------------------
// 3) Factor tables:
//    T[ij][v][k]  (renormalized strand-tilted signatures), 9*1920 floats
//    H[ij][enc][k] = qt[i][k]*qr[j][k]*pe[e][k]*pn[n][k]*pc[c][k], 2880 floats
__global__ __launch_bounds__(256) void factors_kernel(
    const float* __restrict__ T0_, const float* __restrict__ t_,
    const float* __restrict__ r_, const float* __restrict__ e_,
    const float* __restrict__ n_, const float* __restrict__ c_,
    float* __restrict__ T, float* __restrict__ H) {
    __shared__ float T0s[VK], lts[VK], lrs[VK];
    __shared__ float pt[K], pr[K];
    __shared__ float pes[E_DIM * K], pns[N_DIM * K], pcs[C_DIM * K];
    const int tid = threadIdx.x;

    // sigmoids of _t, _r
    for (int idx = tid; idx < VK; idx += 256) {
        lts[idx] = 1.0f / (1.0f + expf(-t_[idx]));
        lrs[idx] = 1.0f / (1.0f + expf(-r_[idx]));
    }
    // T0 = softmax(_T0, axis=0) per column k
    if (tid < K) {
        const int k = tid;
        float mx = -1e30f;
        for (int v = 0; v < V; ++v) mx = fmaxf(mx, T0_[v * K + k]);
        float ssum = 0.f;
        for (int v = 0; v < V; ++v) {
            float ev = expf(T0_[v * K + k] - mx);
            T0s[v * K + k] = ev; ssum += ev;
        }
        for (int v = 0; v < V; ++v) T0s[v * K + k] /= ssum;
    }
    __syncthreads();

    // pt, pr (marginal strand probs) + pe/pn/pc softmaxes
    if (tid < K) {
        const int k = tid;
        float spt = 0.f, spr = 0.f;
        for (int v = 0; v < V; ++v) {
            spt += T0s[v * K + k] * lts[v * K + k];
            spr += T0s[v * K + k] * lrs[v * K + k];
        }
        pt[k] = spt; pr[k] = spr;
        {   // pe: softmax over E_DIM=4
            float m = -1e30f;
            for (int e2 = 0; e2 < E_DIM; ++e2) m = fmaxf(m, e_[e2 * K + k]);
            float se = 0.f; float tmp[E_DIM];
            for (int e2 = 0; e2 < E_DIM; ++e2) { tmp[e2] = expf(e_[e2 * K + k] - m); se += tmp[e2]; }
            for (int e2 = 0; e2 < E_DIM; ++e2) pes[e2 * K + k] = tmp[e2] / se;
        }
        {   // pn: softmax over N_DIM=2
            float m = fmaxf(n_[k], n_[K + k]);
            float a0 = expf(n_[k] - m), a1 = expf(n_[K + k] - m);
            float se = a0 + a1;
            pns[k] = a0 / se; pns[K + k] = a1 / se;
        }
        {   // pc: softmax over C_DIM=2
            float m = fmaxf(c_[k], c_[K + k]);
            float a0 = expf(c_[k] - m), a1 = expf(c_[K + k] - m);
            float se = a0 + a1;
            pcs[k] = a0 / se; pcs[K + k] = a1 / se;
        }
    }
    __syncthreads();

    // T[ij][v][k]: Traw = T0*wt[i]*wr[j], renormalized over V
    for (int id = tid; id < 9 * K; id += 256) {
        const int k = id % K;
        const int ij = id / K;
        const int i = ij / 3, j = ij % 3;
        float ssum = 0.f;
        for (int v = 0; v < V; ++v) {
            float lt = lts[v * K + k], lr = lrs[v * K + k];
            float wt = (i == 0) ? lt : (i == 1) ? (1.0f - lt) : 1.0f;
            float wr = (j == 0) ? lr : (j == 1) ? (1.0f - lr) : 1.0f;
            ssum += T0s[v * K + k] * wt * wr;
        }
        for (int v = 0; v < V; ++v) {
            float lt = lts[v * K + k], lr = lrs[v * K + k];
            float wt = (i == 0) ? lt : (i == 1) ? (1.0f - lt) : 1.0f;
            float wr = (j == 0) ? lr : (j == 1) ? (1.0f - lr) : 1.0f;
            T[(ij * V + v) * K + k] = T0s[v * K + k] * wt * wr / ssum;
        }
    }

    // H[ij][enc][k]
    for (int id = tid; id < 9 * ENC * K; id += 256) {
        const int k = id % K;
        const int enc = (id / K) % ENC;
        const int ij = id / (K * ENC);
        const int i = ij / 3, j = ij % 3;
        const int e2 = enc / 4, n2 = (enc / 2) % 2, c2 = enc % 2;
        float qt = (i == 0) ? pt[k] : (i == 1) ? (1.0f - pt[k]) : 1.0f;
        float qr = (j == 0) ? pr[k] : (j == 1) ? (1.0f - pr[k]) : 1.0f;
        H[id] = qt * qr * pes[e2 * K + k] * pns[n2 * K + k] * pcs[c2 * K + k];
    }
}

// ---------------------------------------------------------------------------
// 4) Main reduction: one 256-thread block per (i,j,e,n,c,b) slab of 1920 floats.
//    s = sum yphi * log(T[ij][v][k] * Fk[k] + eps);  Fk = mr3[i,j,b] * H[ij][enc][k]
__global__ __launch_bounds__(256) void main_kernel(
    const float* __restrict__ yphi, const float* __restrict__ T,
    const float* __restrict__ H, const float* __restrict__ mr,
    const int* __restrict__ index, double* __restrict__ acc) {
    __shared__ __align__(16) float Ts[VK];
    __shared__ __align__(16) float Fk[K];
    __shared__ float wsum[4];
    const int blk = blockIdx.x;
    const int tid = threadIdx.x;
    const int b = blk % B;
    const int encij = blk / B;       // ij*16 + enc
    const int ij = encij / ENC;
    const int i = ij / 3, j = ij % 3;

    if (tid < K) {
        // mi = [0,0,1]: row (i==2), col (j==2)
        float mrv = mr[((int)(i == 2) * 2 + (int)(j == 2)) * D + index[b]];
        Fk[tid] = mrv * H[encij * K + tid];
    }
    // stage T[ij] tile into LDS (float4)
    const float4* __restrict__ Tg = (const float4*)(T + ij * VK);
    float4* Ts4 = (float4*)Ts;
    for (int t = tid; t < VK / 4; t += 256) Ts4[t] = Tg[t];
    __syncthreads();

    const float4* __restrict__ yg = (const float4*)(yphi + (size_t)blk * VK);
    float s = 0.f;
    for (int t = tid; t < VK / 4; t += 256) {  // 480 float4; iter2 has 224 active
        float4 y = yg[t];
        float4 tt = Ts4[t];
        int k0 = (4 * t) % K;                  // in {0,4,8,12,16}: 16B-aligned
        float4 f = *(const float4*)&Fk[k0];
        s += y.x * __logf(tt.x * f.x + EPSF);
        s += y.y * __logf(tt.y * f.y + EPSF);
        s += y.z * __logf(tt.z * f.z + EPSF);
        s += y.w * __logf(tt.w * f.w + EPSF);
    }
#pragma unroll
    for (int off = 32; off; off >>= 1) s += __shfl_down(s, off, 64);
    const int lane = tid & 63, wv = tid >> 6;
    if (lane == 0) wsum[wv] = s;
    __syncthreads();
    if (tid == 0) {
        float tot = wsum[0] + wsum[1] + wsum[2] + wsum[3];
        atomicAdd(&acc[blk & (NSLOTS - 1)], (double)tot);
    }
}

// ---------------------------------------------------------------------------
// 5) fold slots -> scalar output: out = -(sum P_b) / 1920
__global__ void final_kernel(const double* __restrict__ acc, float* __restrict__ out) {
    __shared__ double sh[NSLOTS];
    const int tid = threadIdx.x;
    sh[tid] = acc[tid];
    __syncthreads();
    for (int off = NSLOTS / 2; off; off >>= 1) {
        if (tid < off) sh[tid] += sh[tid + off];
        __syncthreads();
    }
    if (tid == 0) out[0] = (float)(-sh[0] / (double)VK);
}

// ---------------------------------------------------------------------------
extern "C" void kernel_launch(void* const* d_in, const int* in_sizes, int n_in,
                              void* d_out, int out_size, void* d_ws, size_t ws_size,
                              hipStream_t stream) {
    const float* yphi = (const float*)d_in[0];
    const float* Y    = (const float*)d_in[1];
    const float* T0_  = (const float*)d_in[2];
    const float* t_   = (const float*)d_in[3];
    const float* r_   = (const float*)d_in[4];
    const float* e_   = (const float*)d_in[5];
    const float* n_   = (const float*)d_in[6];
    const float* c_   = (const float*)d_in[7];
    const int* index  = (const int*)d_in[8];
    float* out = (float*)d_out;

    char* ws = (char*)d_ws;
    double* acc = (double*)ws;                    // 256 * 8   = 2048 B
    float* y_tr = (float*)(ws + 2048);            // 9216 * 4  = 36864 B  -> 38912
    float* mr   = (float*)(ws + 38912);           // 4096 * 4  = 16384 B  -> 55296
    float* T    = (float*)(ws + 55296);           // 17280 * 4 = 69120 B  -> 124416
    float* H    = (float*)(ws + 124416);          // 2880 * 4  = 11520 B  -> 135936

    hipLaunchKernelGGL(zero_acc_kernel, dim3(1), dim3(NSLOTS), 0, stream, acc);
    hipLaunchKernelGGL(ytr_kernel, dim3(9 * D), dim3(64), 0, stream, Y, y_tr);
    hipLaunchKernelGGL(mr_kernel, dim3(4), dim3(256), 0, stream, y_tr, mr);
    hipLaunchKernelGGL(factors_kernel, dim3(1), dim3(256), 0, stream,
                       T0_, t_, r_, e_, n_, c_, T, H);
    hipLaunchKernelGGL(main_kernel, dim3(NBLK_MAIN), dim3(256), 0, stream,
                       yphi, T, H, mr, index, acc);
    hipLaunchKernelGGL(final_kernel, dim3(1), dim3(NSLOTS), 0, stream, acc, out);
}